// Round 16
// baseline (75.045 us; speedup 1.0000x reference)
//
#include <hip/hip_runtime.h>
#include <math.h>

#define NQ        14
#define DIM       16384      // 2^14
#define BATCHN    128
#define NGATES    13
#define NGEN      15
#define NOBSN     13
#define DEPTHN    4
#define INDIM     256
#define HIDDIM    256
#define ENCDIM    195
#define TCIRC     1024

// Pauli 2x2 matrices (real, imag parts). Order: I, X, Y, Z.
__constant__ float c_PR[4][2][2] = {
  {{1.f, 0.f}, {0.f, 1.f}},   // I
  {{0.f, 1.f}, {1.f, 0.f}},   // X
  {{0.f, 0.f}, {0.f, 0.f}},   // Y (real part)
  {{1.f, 0.f}, {0.f,-1.f}},   // Z
};
__constant__ float c_PI[4][2][2] = {
  {{0.f, 0.f}, {0.f, 0.f}},
  {{0.f, 0.f}, {0.f, 0.f}},
  {{0.f,-1.f}, {1.f, 0.f}},   // Y (imag part)
  {{0.f, 0.f}, {0.f, 0.f}},
};

__device__ __forceinline__ float rfl(float x) {
  return __int_as_float(__builtin_amdgcn_readfirstlane(__float_as_int(x)));
}

// DPP cross-lane (VALU pipe — NOT ds_swizzle).
// 0xB1 = quad xor1, 0x4E = quad xor2, 0x141 = row half-mirror (xor7),
// 0x140 = row mirror (xor15).
template<int CTRL>
__device__ __forceinline__ float fdpp(float v) {
  return __int_as_float(__builtin_amdgcn_mov_dpp(__float_as_int(v), CTRL, 0xF, 0xF, true));
}

// Bank swizzle (R10-15-proven): b0^=y5, b1^=y6^y9, b2^=y5^y7, b3^=y7^y8, b4^=y6.
constexpr int ef_c(int y) {
  return y ^ (((y >> 5) & 1) * 5)
           ^ (((y >> 6) & 1) * 18)
           ^ (((y >> 7) & 1) * 12)
           ^ (((y >> 8) & 1) * 8)
           ^ (((y >> 9) & 1) * 2);
}
// CNOT-chain permutation: sigma(y) = y ^ ((y>>1)&8191); inverse = suffix fold.
constexpr int siginv_c(int z) {
  int t = z;
  t ^= t >> 1; t ^= t >> 2; t ^= t >> 4; t ^= t >> 8;
  return t & 16383;
}
// inverse of the z-bits-13..10 -> y-bits-13..10 map: yinv(j) = j ^ (j>>1).
// NOTE (R14 post-mortem): parity(yinv(j)) == j0 == y10, and the register set's
// low y-bits depend on parity(i) — so ONLY obs with y10 fixed inside their
// pairs (obs0: y13,y12; obs1: y12,y11) are register-local in the FINAL pass.
// obs2 (y11,y10) is NOT (y10 flips) — it must go through LDS.
constexpr int yinv_c(int j) { return (j ^ (j >> 1)) & 15; }

// quadratic-form amp index for a 2-qubit pair inside a 4-bit window:
// MODE 0: pair at k bits (3,2); MODE 1: bits (2,1); MODE 2: bits (1,0).
constexpr int qidx(int MODE, int i, int s) {
  return MODE == 0 ? ((i << 2) | s)
       : MODE == 1 ? (((s >> 1) << 3) | (i << 1) | (s & 1))
       : ((s << 2) | i);
}

// <v|H|v> over 16 amps for one obs; H compressed to diag + upper triangle.
// YM: compose the yinv register-index permutation into the index map
// (FINAL perm pass; avoids materializing a 32-reg copy -> no spill).
template<int MODE, bool YM>
__device__ __forceinline__ float qform16(const float2* __restrict__ hp,
                                         const float vr[16], const float vi[16]) {
  const int ui[6] = {0, 0, 0, 1, 1, 2};
  const int uj[6] = {1, 2, 3, 2, 3, 3};
  float dH[4], oR[6], oI[6];
  #pragma unroll
  for (int i = 0; i < 4; ++i) dH[i] = rfl(hp[i * 5].x);
  #pragma unroll
  for (int u = 0; u < 6; ++u) {
    oR[u] = rfl(2.f * hp[ui[u] * 4 + uj[u]].x);
    oI[u] = rfl(2.f * hp[ui[u] * 4 + uj[u]].y);
  }
  float acc = 0.f;
  #pragma unroll
  for (int s = 0; s < 4; ++s) {
    #pragma unroll
    for (int i = 0; i < 4; ++i) {
      const int k0 = qidx(MODE, i, s);
      const int k = YM ? yinv_c(k0) : k0;
      acc = fmaf(dH[i], fmaf(vr[k], vr[k], vi[k] * vi[k]), acc);
    }
    #pragma unroll
    for (int u = 0; u < 6; ++u) {
      const int a0 = qidx(MODE, ui[u], s), b0 = qidx(MODE, uj[u], s);
      const int a = YM ? yinv_c(a0) : a0, b2 = YM ? yinv_c(b0) : b0;
      const float p = fmaf(vr[a], vr[b2], vi[a] * vi[b2]);
      const float q = fmaf(vr[a], vi[b2], -(vi[a] * vr[b2]));
      acc = fmaf(oR[u], p, fmaf(-oI[u], q, acc));
    }
  }
  return acc;
}

// ---- common gate-pair body on 16 in-register amps ----
__device__ __forceinline__ void gate_pair16(const float2* __restrict__ ugA,
                                            const float2* __restrict__ ugB,
                                            float vr[16], float vi[16]) {
  {  // gate A on k-bits (3,2)
    float ur[16], ui_[16];
    #pragma unroll
    for (int i = 0; i < 16; ++i) { ur[i] = rfl(ugA[i].x); ui_[i] = rfl(ugA[i].y); }
    #pragma unroll
    for (int r = 0; r < 4; ++r) {
      float tr[4], ti_[4];
      #pragma unroll
      for (int i = 0; i < 4; ++i) {
        float sr = 0.f, si = 0.f;
        #pragma unroll
        for (int l = 0; l < 4; ++l) {
          const int kl = (l << 2) | r;
          sr = fmaf(ur[i * 4 + l], vr[kl], fmaf(-ui_[i * 4 + l], vi[kl], sr));
          si = fmaf(ur[i * 4 + l], vi[kl], fmaf(ui_[i * 4 + l], vr[kl], si));
        }
        tr[i] = sr; ti_[i] = si;
      }
      #pragma unroll
      for (int i = 0; i < 4; ++i) { vr[(i << 2) | r] = tr[i]; vi[(i << 2) | r] = ti_[i]; }
    }
  }
  {  // gate B on k-bits (1,0)
    float ur[16], ui_[16];
    #pragma unroll
    for (int i = 0; i < 16; ++i) { ur[i] = rfl(ugB[i].x); ui_[i] = rfl(ugB[i].y); }
    #pragma unroll
    for (int r = 0; r < 4; ++r) {
      float tr[4], ti_[4];
      #pragma unroll
      for (int i = 0; i < 4; ++i) {
        float sr = 0.f, si = 0.f;
        #pragma unroll
        for (int l = 0; l < 4; ++l) {
          const int kl = (r << 2) | l;
          sr = fmaf(ur[i * 4 + l], vr[kl], fmaf(-ui_[i * 4 + l], vi[kl], sr));
          si = fmaf(ur[i * 4 + l], vi[kl], fmaf(ui_[i * 4 + l], vr[kl], si));
        }
        tr[i] = sr; ti_[i] = si;
      }
      #pragma unroll
      for (int i = 0; i < 4; ++i) { vr[(r << 2) | i] = tr[i]; vi[(r << 2) | i] = ti_[i]; }
    }
  }
}

// ---- FUSED init + pair9 (R13-proven): closed-form product state + q1,q3 ----
__device__ __forceinline__ void init_pair9(float2* __restrict__ st,
                                           const float2* __restrict__ Ush,
                                           int tid) {
  const int t9 = (tid >> 9) & 1, t8 = (tid >> 8) & 1;   // wave-uniform
  const int t76 = (tid >> 6) & 3;                        // wave-uniform
  const int t54 = (tid >> 4) & 3, t32 = (tid >> 2) & 3, t10 = tid & 3;
  float f0r[2], f0i[2];
  #pragma unroll
  for (int k3 = 0; k3 < 2; ++k3) {
    f0r[k3] = rfl(Ush[0 * 16 + ((t9 << 1) | k3) * 4].x);
    f0i[k3] = rfl(Ush[0 * 16 + ((t9 << 1) | k3) * 4].y);
  }
  float f1r[4], f1i[4];
  #pragma unroll
  for (int j = 0; j < 4; ++j) {
    f1r[j] = rfl(Ush[1 * 16 + j * 4].x);
    f1i[j] = rfl(Ush[1 * 16 + j * 4].y);
  }
  float f2r[2], f2i[2];
  #pragma unroll
  for (int k0 = 0; k0 < 2; ++k0) {
    f2r[k0] = rfl(Ush[2 * 16 + ((k0 << 1) | t8) * 4].x);
    f2i[k0] = rfl(Ush[2 * 16 + ((k0 << 1) | t8) * 4].y);
  }
  const float f3r = rfl(Ush[3 * 16 + t76 * 4].x), f3i = rfl(Ush[3 * 16 + t76 * 4].y);
  const float2 f4 = Ush[4 * 16 + t54 * 4];
  const float2 f5 = Ush[5 * 16 + t32 * 4];
  const float2 f6 = Ush[6 * 16 + t10 * 4];
  float cr = f3r * f4.x - f3i * f4.y, ci = f3r * f4.y + f3i * f4.x, tr, ti;
  tr = cr * f5.x - ci * f5.y; ti = cr * f5.y + ci * f5.x; cr = tr; ci = ti;
  tr = cr * f6.x - ci * f6.y; ti = cr * f6.y + ci * f6.x; cr = tr; ci = ti;
  float g2r[2], g2i[2];
  #pragma unroll
  for (int k0 = 0; k0 < 2; ++k0) {
    g2r[k0] = f2r[k0] * cr - f2i[k0] * ci;
    g2i[k0] = f2r[k0] * ci + f2i[k0] * cr;
  }
  float vr[16], vi[16];
  #pragma unroll
  for (int k = 0; k < 16; ++k) {
    const int k3 = k >> 3, k21 = (k >> 1) & 3, k0 = k & 1;
    const float hr2 = f0r[k3] * f1r[k21] - f0i[k3] * f1i[k21];
    const float hi2 = f0r[k3] * f1i[k21] + f0i[k3] * f1r[k21];
    vr[k] = hr2 * g2r[k0] - hi2 * g2i[k0];
    vi[k] = hr2 * g2i[k0] + hi2 * g2r[k0];
  }
  gate_pair16(Ush + 7 * 16, Ush + 8 * 16, vr, vi);   // q1 (bits 12,11), q3 (10,9)
  constexpr int m = (1 << 9) - 1;
  const int a0 = ef_c(((tid & ~m) << 4) | (tid & m));
  #pragma unroll
  for (int k = 0; k < 16; ++k)
    st[a0 ^ ef_c(k << 9)] = make_float2(vr[k], vi[k]);
  __syncthreads();
}

// ---- WAVE-LOCAL SU4 pair pass (SH+4 <= 10): NO barrier ----
template<int SH>
__device__ __forceinline__ void su4_pairW(float2* __restrict__ st,
                                          const float2* __restrict__ ugA,
                                          const float2* __restrict__ ugB,
                                          int tid) {
  const int w = tid >> 6, l = tid & 63;
  constexpr int m = (1 << SH) - 1;
  const int a0 = ef_c((w << 10) | ((l & ~m) << 4) | (l & m));
  float vr[16], vi[16];
  #pragma unroll
  for (int k = 0; k < 16; ++k) {
    const float2 v = st[a0 ^ ef_c(k << SH)];
    vr[k] = v.x; vi[k] = v.y;
  }
  gate_pair16(ugA, ugB, vr, vi);
  #pragma unroll
  for (int k = 0; k < 16; ++k)
    st[a0 ^ ef_c(k << SH)] = make_float2(vr[k], vi[k]);
}

template<int J>
__device__ __forceinline__ void bfly16(float c, float s, float pr[16], float pi_[16]) {
  #pragma unroll
  for (int i = 0; i < 16; ++i) {
    if ((i & (1 << J)) == 0) {
      const int j = i | (1 << J);
      const float ar = pr[i], ai = pi_[i], br = pr[j], bi = pi_[j];
      pr[i]  = fmaf(c, ar, -(s * br));
      pi_[i] = fmaf(c, ai, -(s * bi));
      pr[j]  = fmaf(s, ar, c * br);
      pi_[j] = fmaf(s, ai, c * bi);
    }
  }
}

// ---- WAVE-LOCAL 4-qubit RY pass at SH=6 (qubits 4..7): NO barrier ----
__device__ __forceinline__ void ry4W6(float2* __restrict__ st,
                                      const float* __restrict__ rc,
                                      const float* __restrict__ rs, int tid) {
  const float c3 = rfl(rc[4]), s3 = rfl(rs[4]);
  const float c2 = rfl(rc[5]), s2 = rfl(rs[5]);
  const float c1 = rfl(rc[6]), s1 = rfl(rs[6]);
  const float c0 = rfl(rc[7]), s0 = rfl(rs[7]);
  const int w = tid >> 6, l = tid & 63;
  const int a0 = ef_c((w << 10) | l);   // SH=6: (l&~63)<<4 == 0
  float vr[16], vi[16];
  #pragma unroll
  for (int k = 0; k < 16; ++k) {
    const float2 v = st[a0 ^ ef_c(k << 6)];
    vr[k] = v.x; vi[k] = v.y;
  }
  bfly16<3>(c3, s3, vr, vi);
  bfly16<2>(c2, s2, vr, vi);
  bfly16<1>(c1, s1, vr, vi);
  bfly16<0>(c0, s0, vr, vi);
  #pragma unroll
  for (int k = 0; k < 16; ++k)
    st[a0 ^ ef_c(k << 6)] = make_float2(vr[k], vi[k]);
}

// ---- WAVE-LOCAL RY pass at SH=2 (qubits 8..11) + DPP butterflies for
// qubits 12,13 (y-bits 1,0 = lane bits 1,0, quad-aligned). R13-proven.
__device__ __forceinline__ void ry4W2d(float2* __restrict__ st,
                                       const float* __restrict__ rc,
                                       const float* __restrict__ rs, int tid) {
  const float c3 = rfl(rc[8]),  s3 = rfl(rs[8]);
  const float c2 = rfl(rc[9]),  s2 = rfl(rs[9]);
  const float c1 = rfl(rc[10]), s1 = rfl(rs[10]);
  const float c0 = rfl(rc[11]), s0 = rfl(rs[11]);
  const float cA = rfl(rc[12]), sA = rfl(rs[12]);   // qubit 12 -> y bit 1
  const float cB = rfl(rc[13]), sB = rfl(rs[13]);   // qubit 13 -> y bit 0
  const int w = tid >> 6, l = tid & 63;
  const int a0 = ef_c((w << 10) | ((l & ~3) << 4) | (l & 3));
  float vr[16], vi[16];
  #pragma unroll
  for (int k = 0; k < 16; ++k) {
    const float2 v = st[a0 ^ ef_c(k << 2)];
    vr[k] = v.x; vi[k] = v.y;
  }
  bfly16<3>(c3, s3, vr, vi);
  bfly16<2>(c2, s2, vr, vi);
  bfly16<1>(c1, s1, vr, vi);
  bfly16<0>(c0, s0, vr, vi);
  {
    const float se = (l & 1) ? sB : -sB;
    #pragma unroll
    for (int k = 0; k < 16; ++k) {
      const float pr = fdpp<0xB1>(vr[k]), pi_ = fdpp<0xB1>(vi[k]);
      vr[k] = fmaf(cB, vr[k], se * pr);
      vi[k] = fmaf(cB, vi[k], se * pi_);
    }
  }
  {
    const float se = (l & 2) ? sA : -sA;
    #pragma unroll
    for (int k = 0; k < 16; ++k) {
      const float pr = fdpp<0x4E>(vr[k]), pi_ = fdpp<0x4E>(vi[k]);
      vr[k] = fmaf(cA, vr[k], se * pr);
      vi[k] = fmaf(cA, vi[k], se * pi_);
    }
  }
  #pragma unroll
  for (int k = 0; k < 16; ++k)
    st[a0 ^ ef_c(k << 2)] = make_float2(vr[k], vi[k]);
}

// ---- block reduce: 4 DPP (VALU) + 2 shfl_xor stages; xor masks {1,2,7,15,16,32}
// span all 64 lanes (group-generated). Saves 4 LDS-pipe ops per reduce.
__device__ __forceinline__ void reduce_store(float a, float* slot, int lane, int wid) {
  a += fdpp<0xB1>(a);    // xor 1
  a += fdpp<0x4E>(a);    // xor 2
  a += fdpp<0x141>(a);   // half-mirror = xor 7
  a += fdpp<0x140>(a);   // mirror = xor 15
  a += __shfl_xor(a, 16, 64);
  a += __shfl_xor(a, 32, 64);
  if (lane == 0) slot[wid] = a;
}

// ---- fused RY(q0..3) + CNOT-chain pass.
// FINAL: obs0, obs1 ONLY (both have y10 fixed inside pairs -> register-local;
// obs2 flips y10 -> must go through LDS: R14's bug). YM index map, no copy.
template<bool FINAL>
__device__ __forceinline__ void perm_ry_pass(float2* __restrict__ st,
                                             const float* __restrict__ rc,
                                             const float* __restrict__ rs,
                                             int tid,
                                             const float2* __restrict__ Hsh,
                                             float (*red)[TCIRC / 64],
                                             int lane, int wid) {
  const float c0 = rfl(rc[0]), s0 = rfl(rs[0]);
  const float c1 = rfl(rc[1]), s1 = rfl(rs[1]);
  const float c2 = rfl(rc[2]), s2 = rfl(rs[2]);
  const float c3 = rfl(rc[3]), s3 = rfl(rs[3]);
  __syncthreads();   // wave-local writers from prior passes must land
  const int Er = ef_c(tid);
  float pr[16], pi_[16];
  #pragma unroll
  for (int i = 0; i < 16; ++i) {
    const float2 v = st[Er ^ ef_c(i << 10)];
    pr[i] = v.x; pi_[i] = v.y;
  }
  __syncthreads();
  bfly16<3>(c0, s0, pr, pi_);
  bfly16<2>(c1, s1, pr, pi_);
  bfly16<1>(c2, s2, pr, pi_);
  bfly16<0>(c3, s3, pr, pi_);
  const int Ew = ef_c(siginv_c(tid));
  #pragma unroll
  for (int i = 0; i < 16; ++i)
    st[Ew ^ ef_c(siginv_c(i << 10))] = make_float2(pr[i], pi_[i]);
  if (FINAL) {
    reduce_store(qform16<0, true>(Hsh + 0 * 16, pr, pi_), red[0], lane, wid); // y13,y12
    reduce_store(qform16<1, true>(Hsh + 1 * 16, pr, pi_), red[1], lane, wid); // y12,y11
  }
  __syncthreads();
}

// ---- obs window pass: 4-bit window bits SH+3..SH (R12-proven tiling) ----
// NOB==3: MODE0/1/2 at obase..obase+2. NOB==2: MODE1, MODE2 (SH=0: obs11,12).
template<int SH, int NOB>
__device__ __forceinline__ void obs_tri(const float2* __restrict__ st,
                                        const float2* __restrict__ Hsh, int obase,
                                        float (*red)[TCIRC / 64],
                                        int lane, int wid, int tid) {
  constexpr int m = (1 << SH) - 1;
  const int a0 = ef_c(((tid & ~m) << 4) | (tid & m));
  float vr[16], vi[16];
  #pragma unroll
  for (int k = 0; k < 16; ++k) {
    const float2 v = st[a0 ^ ef_c(k << SH)];
    vr[k] = v.x; vi[k] = v.y;
  }
  if (NOB == 3) {
    reduce_store(qform16<0, false>(Hsh + (obase + 0) * 16, vr, vi), red[obase + 0], lane, wid);
    reduce_store(qform16<1, false>(Hsh + (obase + 1) * 16, vr, vi), red[obase + 1], lane, wid);
    reduce_store(qform16<2, false>(Hsh + (obase + 2) * 16, vr, vi), red[obase + 2], lane, wid);
  } else {
    reduce_store(qform16<1, false>(Hsh + (obase + 0) * 16, vr, vi), red[obase + 0], lane, wid);
    reduce_store(qform16<2, false>(Hsh + (obase + 1) * 16, vr, vi), red[obase + 1], lane, wid);
  }
}

// ====== single fused kernel: encoder + U-build (shfl-parallel) + circuit ====
__launch_bounds__(TCIRC, 1)
__global__ void circuit_kernel(const float* __restrict__ x,
                               const float* __restrict__ W1,
                               const float* __restrict__ b1,
                               const float* __restrict__ W2,
                               const float* __restrict__ b2,
                               const float* __restrict__ vp,
                               const float* __restrict__ oA,
                               const float* __restrict__ oB,
                               const float* __restrict__ oD,
                               float* __restrict__ out) {
  __shared__ float2 st[DIM];                 // 128 KiB (head: scratch overlay)
  __shared__ float2 Ush[NGATES * 16];
  __shared__ float2 Hsh[NOBSN * 16];
  __shared__ float  ryc[DEPTHN * NQ];
  __shared__ float  rys[DEPTHN * NQ];
  __shared__ float  red[NOBSN][TCIRC / 64];

  const int b = blockIdx.x;
  const int tid = threadIdx.x;

  // ---- head scratch overlaid on the not-yet-initialized state ----
  float* base = (float*)st;
  float* hrow = base + 256;    // 256
  float* encs = base + 512;    // 195
  float* part = base + 1024;   // 1024

  // trig + observable H on disjoint high threads (independent of encoder)
  if (tid >= 960 && tid < 960 + DEPTHN * NQ) {
    const int i = tid - 960;
    const float h = 0.5f * vp[i];
    ryc[i] = cosf(h); rys[i] = sinf(h);
  }
  if (tid >= 832 && tid < 832 + NOBSN) {
    const int o = tid - 832;
    const int rr[6] = {1, 2, 2, 3, 3, 3};
    const int cc[6] = {0, 0, 1, 0, 1, 2};
    float2 H[16];
    #pragma unroll
    for (int i = 0; i < 16; ++i) H[i] = make_float2(0.f, 0.f);
    for (int m = 0; m < 6; ++m) {
      const float a = oA[o * 6 + m], bb = oB[o * 6 + m];
      H[rr[m] * 4 + cc[m]] = make_float2(a, bb);
      H[cc[m] * 4 + rr[m]] = make_float2(a, -bb);
    }
    H[0]  = make_float2(2.f * oD[o * 4 + 1], 0.f);
    H[5]  = make_float2(2.f * oD[o * 4 + 2], 0.f);
    H[10] = make_float2(2.f * oD[o * 4 + 3], 0.f);
    for (int i = 0; i < 16; ++i) Hsh[o * 16 + i] = H[i];
  }

  {  // hrow partials: 4 threads per output, float4 loads; x read DIRECTLY
     // from global (wave-uniform address per lane group -> L2 broadcast).
     // Removes the xrow LDS staging + its barrier (R16 change).
    const int o = tid & 255, q = tid >> 8;
    const float4* wp = (const float4*)(W1 + o * INDIM + q * 64);
    const float4* xq = (const float4*)(x + b * INDIM + q * 64);
    float a = 0.f;
    #pragma unroll 4
    for (int k = 0; k < 16; ++k) {
      const float4 wv = wp[k], xv = xq[k];
      a = fmaf(wv.x, xv.x, fmaf(wv.y, xv.y, fmaf(wv.z, xv.z, fmaf(wv.w, xv.w, a))));
    }
    part[(q << 8) | o] = a;
  }
  __syncthreads();
  if (tid < HIDDIM) {
    const float a = b1[tid] + part[tid] + part[256 + tid] + part[512 + tid] + part[768 + tid];
    hrow[tid] = a / (1.f + expf(-a));
  }
  __syncthreads();
  {  // enc partials
    const int o = tid & 255, q = tid >> 8;
    if (o < ENCDIM) {
      const float4* wp = (const float4*)(W2 + o * HIDDIM + q * 64);
      const float4* hq = (const float4*)(hrow + q * 64);
      float a = 0.f;
      #pragma unroll 4
      for (int k = 0; k < 16; ++k) {
        const float4 wv = wp[k], hv = hq[k];
        a = fmaf(wv.x, hv.x, fmaf(wv.y, hv.y, fmaf(wv.z, hv.z, fmaf(wv.w, hv.w, a))));
      }
      part[(q << 8) | o] = a;
    }
  }
  __syncthreads();
  if (tid < ENCDIM)
    encs[tid] = b2[tid] + part[tid] + part[256 + tid] + part[512 + tid] + part[768 + tid];
  __syncthreads();

  // ---- U-build: 16 lanes per gate, matmuls via shfl (no barriers inside) ----
  if (tid < NGATES * 16) {
    const int g = tid >> 4, e = tid & 15, i = e >> 2, j = e & 3;
    const float* th = encs + g * NGEN;
    float Are = 0.f, Aie = 0.f;
    for (int t = 0; t < NGEN; ++t) {
      const int p = t + 1;
      const int pa = p >> 2, pb = p & 3;
      const float ar = c_PR[pa][i >> 1][j >> 1], ai = c_PI[pa][i >> 1][j >> 1];
      const float br = c_PR[pb][i & 1][j & 1],  bi = c_PI[pb][i & 1][j & 1];
      Are = fmaf(th[t], ar * br - ai * bi, Are);
      Aie = fmaf(th[t], ar * bi + ai * br, Aie);
    }
    float r = sqrtf(Are * Are + Aie * Aie);
    r += __shfl_xor(r, 1, 16);
    r += __shfl_xor(r, 2, 16);
    float nrm = r;
    nrm = fmaxf(nrm, __shfl_xor(nrm, 4, 16));
    nrm = fmaxf(nrm, __shfl_xor(nrm, 8, 16));
    int sct = 0;
    float scale = 1.f;
    while (nrm * scale > 0.5f && sct < 30) { scale *= 0.5f; ++sct; }
    const float Mre = -Aie * scale, Mie = Are * scale;   // M = i*A*scale
    float Rr = (i == j) ? 1.f : 0.f, Ri = 0.f;
    for (int k = 10; k >= 1; --k) {
      const float inv = 1.f / (float)k;
      float tr = 0.f, ti = 0.f;
      #pragma unroll
      for (int l = 0; l < 4; ++l) {
        const float mr = __shfl(Mre, i * 4 + l, 16), mi = __shfl(Mie, i * 4 + l, 16);
        const float rr2 = __shfl(Rr, l * 4 + j, 16), ri2 = __shfl(Ri, l * 4 + j, 16);
        tr = fmaf(mr, rr2, fmaf(-mi, ri2, tr));
        ti = fmaf(mr, ri2, fmaf(mi, rr2, ti));
      }
      Rr = ((i == j) ? 1.f : 0.f) + inv * tr;
      Ri = inv * ti;
    }
    for (int it = 0; it < sct; ++it) {
      float tr = 0.f, ti = 0.f;
      #pragma unroll
      for (int l = 0; l < 4; ++l) {
        const float ar = __shfl(Rr, i * 4 + l, 16), ai2 = __shfl(Ri, i * 4 + l, 16);
        const float br = __shfl(Rr, l * 4 + j, 16), bi2 = __shfl(Ri, l * 4 + j, 16);
        tr = fmaf(ar, br, fmaf(-ai2, bi2, tr));
        ti = fmaf(ar, bi2, fmaf(ai2, br, ti));
      }
      Rr = tr; Ri = ti;
    }
    Ush[g * 16 + e] = make_float2(Rr, Ri);
  }
  __syncthreads();

  // ---- fused: even-layer product state + odd gates q1,q3 (one pass, 0 reads)
  init_pair9(st, Ush, tid);

  // ---- remaining odd layer: 2 wave-local passes ----
  su4_pairW<5>(st, Ush + 9 * 16, Ush + 10 * 16, tid);  // q5,q7 (bits 8..5)
  su4_pairW<1>(st, Ush + 11 * 16, Ush + 12 * 16, tid); // q9,q11 (bits 4..1)

  // ---- variational depths: 2 wave-local RY passes + fused perm+RY(0..3) ----
  const int lane = tid & 63, wid = tid >> 6;
  #pragma unroll 1
  for (int d = 0; d < DEPTHN - 1; ++d) {
    const float* rc = ryc + d * NQ;
    const float* rs = rys + d * NQ;
    ry4W6(st, rc, rs, tid);                                // qubits 4..7
    ry4W2d(st, rc, rs, tid);                               // qubits 8..13 (DPP)
    perm_ry_pass<false>(st, rc, rs, tid, Hsh, red, lane, wid);
  }
  {  // final depth: perm pass also computes obs0, obs1 in-register
    const float* rc = ryc + (DEPTHN - 1) * NQ;
    const float* rs = rys + (DEPTHN - 1) * NQ;
    ry4W6(st, rc, rs, tid);
    ry4W2d(st, rc, rs, tid);
    perm_ry_pass<true>(st, rc, rs, tid, Hsh, red, lane, wid);
  }

  // ---- remaining observables: 4 read-only window passes (R12-proven tiling)
  obs_tri<8, 3>(st, Hsh, 2, red, lane, wid, tid);   // obs2 (11,10), obs3, obs4
  obs_tri<5, 3>(st, Hsh, 5, red, lane, wid, tid);   // obs5 (8,7),  obs6, obs7
  obs_tri<2, 3>(st, Hsh, 8, red, lane, wid, tid);   // obs8 (5,4),  obs9, obs10
  obs_tri<0, 2>(st, Hsh, 11, red, lane, wid, tid);  // obs11 (2,1), obs12 (1,0)

  __syncthreads();
  if (tid < NOBSN) {
    float s = 0.f;
    #pragma unroll
    for (int w = 0; w < TCIRC / 64; ++w) s += red[tid][w];
    out[b * NOBSN + tid] = s;
  }
}

extern "C" void kernel_launch(void* const* d_in, const int* in_sizes, int n_in,
                              void* d_out, int out_size, void* d_ws, size_t ws_size,
                              hipStream_t stream) {
  const float* x  = (const float*)d_in[0];
  const float* W1 = (const float*)d_in[1];
  const float* b1 = (const float*)d_in[2];
  const float* W2 = (const float*)d_in[3];
  const float* b2 = (const float*)d_in[4];
  const float* vp = (const float*)d_in[5];
  const float* oA = (const float*)d_in[6];
  const float* oB = (const float*)d_in[7];
  const float* oD = (const float*)d_in[8];
  float* out = (float*)d_out;

  circuit_kernel<<<BATCHN, TCIRC, 0, stream>>>(x, W1, b1, W2, b2, vp, oA, oB, oD, out);
}

// Round 17
// 73.671 us; speedup vs baseline: 1.0187x; 1.0187x over previous
//
#include <hip/hip_runtime.h>
#include <math.h>

#define NQ        14
#define DIM       16384      // 2^14
#define BATCHN    128
#define NGATES    13
#define NGEN      15
#define NOBSN     13
#define DEPTHN    4
#define INDIM     256
#define HIDDIM    256
#define ENCDIM    195
#define TCIRC     1024

// Pauli 2x2 matrices (real, imag parts). Order: I, X, Y, Z.
__constant__ float c_PR[4][2][2] = {
  {{1.f, 0.f}, {0.f, 1.f}},   // I
  {{0.f, 1.f}, {1.f, 0.f}},   // X
  {{0.f, 0.f}, {0.f, 0.f}},   // Y (real part)
  {{1.f, 0.f}, {0.f,-1.f}},   // Z
};
__constant__ float c_PI[4][2][2] = {
  {{0.f, 0.f}, {0.f, 0.f}},
  {{0.f, 0.f}, {0.f, 0.f}},
  {{0.f,-1.f}, {1.f, 0.f}},   // Y (imag part)
  {{0.f, 0.f}, {0.f, 0.f}},
};

__device__ __forceinline__ float rfl(float x) {
  return __int_as_float(__builtin_amdgcn_readfirstlane(__float_as_int(x)));
}

// DPP cross-lane (VALU pipe — NOT ds_swizzle).
// 0xB1 = quad xor1, 0x4E = quad xor2, 0x141 = row half-mirror (xor7),
// 0x140 = row mirror (xor15).
template<int CTRL>
__device__ __forceinline__ float fdpp(float v) {
  return __int_as_float(__builtin_amdgcn_mov_dpp(__float_as_int(v), CTRL, 0xF, 0xF, true));
}

// Bank swizzle (R10-15-proven): b0^=y5, b1^=y6^y9, b2^=y5^y7, b3^=y7^y8, b4^=y6.
constexpr int ef_c(int y) {
  return y ^ (((y >> 5) & 1) * 5)
           ^ (((y >> 6) & 1) * 18)
           ^ (((y >> 7) & 1) * 12)
           ^ (((y >> 8) & 1) * 8)
           ^ (((y >> 9) & 1) * 2);
}
// CNOT-chain permutation: sigma(y) = y ^ ((y>>1)&8191); inverse = suffix fold.
constexpr int siginv_c(int z) {
  int t = z;
  t ^= t >> 1; t ^= t >> 2; t ^= t >> 4; t ^= t >> 8;
  return t & 16383;
}
// inverse of the z-bits-13..10 -> y-bits-13..10 map: yinv(j) = j ^ (j>>1).
// NOTE (R14 post-mortem): parity(yinv(j)) == j0 == y10, and the register set's
// low y-bits depend on parity(i) — so ONLY obs with y10 fixed inside their
// pairs (obs0: y13,y12; obs1: y12,y11) are register-local in the FINAL pass.
// obs2 (y11,y10) is NOT (y10 flips) — it must go through LDS.
constexpr int yinv_c(int j) { return (j ^ (j >> 1)) & 15; }

// quadratic-form amp index for a 2-qubit pair inside a 4-bit window:
// MODE 0: pair at k bits (3,2); MODE 1: bits (2,1); MODE 2: bits (1,0).
constexpr int qidx(int MODE, int i, int s) {
  return MODE == 0 ? ((i << 2) | s)
       : MODE == 1 ? (((s >> 1) << 3) | (i << 1) | (s & 1))
       : ((s << 2) | i);
}

// <v|H|v> over 16 amps for one obs; H compressed to diag + upper triangle.
// YM: compose the yinv register-index permutation into the index map
// (FINAL perm pass; avoids materializing a 32-reg copy -> no spill).
template<int MODE, bool YM>
__device__ __forceinline__ float qform16(const float2* __restrict__ hp,
                                         const float vr[16], const float vi[16]) {
  const int ui[6] = {0, 0, 0, 1, 1, 2};
  const int uj[6] = {1, 2, 3, 2, 3, 3};
  float dH[4], oR[6], oI[6];
  #pragma unroll
  for (int i = 0; i < 4; ++i) dH[i] = rfl(hp[i * 5].x);
  #pragma unroll
  for (int u = 0; u < 6; ++u) {
    oR[u] = rfl(2.f * hp[ui[u] * 4 + uj[u]].x);
    oI[u] = rfl(2.f * hp[ui[u] * 4 + uj[u]].y);
  }
  float acc = 0.f;
  #pragma unroll
  for (int s = 0; s < 4; ++s) {
    #pragma unroll
    for (int i = 0; i < 4; ++i) {
      const int k0 = qidx(MODE, i, s);
      const int k = YM ? yinv_c(k0) : k0;
      acc = fmaf(dH[i], fmaf(vr[k], vr[k], vi[k] * vi[k]), acc);
    }
    #pragma unroll
    for (int u = 0; u < 6; ++u) {
      const int a0 = qidx(MODE, ui[u], s), b0 = qidx(MODE, uj[u], s);
      const int a = YM ? yinv_c(a0) : a0, b2 = YM ? yinv_c(b0) : b0;
      const float p = fmaf(vr[a], vr[b2], vi[a] * vi[b2]);
      const float q = fmaf(vr[a], vi[b2], -(vi[a] * vr[b2]));
      acc = fmaf(oR[u], p, fmaf(-oI[u], q, acc));
    }
  }
  return acc;
}

// ---- common gate-pair body on 16 in-register amps ----
__device__ __forceinline__ void gate_pair16(const float2* __restrict__ ugA,
                                            const float2* __restrict__ ugB,
                                            float vr[16], float vi[16]) {
  {  // gate A on k-bits (3,2)
    float ur[16], ui_[16];
    #pragma unroll
    for (int i = 0; i < 16; ++i) { ur[i] = rfl(ugA[i].x); ui_[i] = rfl(ugA[i].y); }
    #pragma unroll
    for (int r = 0; r < 4; ++r) {
      float tr[4], ti_[4];
      #pragma unroll
      for (int i = 0; i < 4; ++i) {
        float sr = 0.f, si = 0.f;
        #pragma unroll
        for (int l = 0; l < 4; ++l) {
          const int kl = (l << 2) | r;
          sr = fmaf(ur[i * 4 + l], vr[kl], fmaf(-ui_[i * 4 + l], vi[kl], sr));
          si = fmaf(ur[i * 4 + l], vi[kl], fmaf(ui_[i * 4 + l], vr[kl], si));
        }
        tr[i] = sr; ti_[i] = si;
      }
      #pragma unroll
      for (int i = 0; i < 4; ++i) { vr[(i << 2) | r] = tr[i]; vi[(i << 2) | r] = ti_[i]; }
    }
  }
  {  // gate B on k-bits (1,0)
    float ur[16], ui_[16];
    #pragma unroll
    for (int i = 0; i < 16; ++i) { ur[i] = rfl(ugB[i].x); ui_[i] = rfl(ugB[i].y); }
    #pragma unroll
    for (int r = 0; r < 4; ++r) {
      float tr[4], ti_[4];
      #pragma unroll
      for (int i = 0; i < 4; ++i) {
        float sr = 0.f, si = 0.f;
        #pragma unroll
        for (int l = 0; l < 4; ++l) {
          const int kl = (r << 2) | l;
          sr = fmaf(ur[i * 4 + l], vr[kl], fmaf(-ui_[i * 4 + l], vi[kl], sr));
          si = fmaf(ur[i * 4 + l], vi[kl], fmaf(ui_[i * 4 + l], vr[kl], si));
        }
        tr[i] = sr; ti_[i] = si;
      }
      #pragma unroll
      for (int i = 0; i < 4; ++i) { vr[(r << 2) | i] = tr[i]; vi[(r << 2) | i] = ti_[i]; }
    }
  }
}

// ---- FUSED init + pair9 (R13-proven): closed-form product state + q1,q3 ----
__device__ __forceinline__ void init_pair9(float2* __restrict__ st,
                                           const float2* __restrict__ Ush,
                                           int tid) {
  const int t9 = (tid >> 9) & 1, t8 = (tid >> 8) & 1;   // wave-uniform
  const int t76 = (tid >> 6) & 3;                        // wave-uniform
  const int t54 = (tid >> 4) & 3, t32 = (tid >> 2) & 3, t10 = tid & 3;
  float f0r[2], f0i[2];
  #pragma unroll
  for (int k3 = 0; k3 < 2; ++k3) {
    f0r[k3] = rfl(Ush[0 * 16 + ((t9 << 1) | k3) * 4].x);
    f0i[k3] = rfl(Ush[0 * 16 + ((t9 << 1) | k3) * 4].y);
  }
  float f1r[4], f1i[4];
  #pragma unroll
  for (int j = 0; j < 4; ++j) {
    f1r[j] = rfl(Ush[1 * 16 + j * 4].x);
    f1i[j] = rfl(Ush[1 * 16 + j * 4].y);
  }
  float f2r[2], f2i[2];
  #pragma unroll
  for (int k0 = 0; k0 < 2; ++k0) {
    f2r[k0] = rfl(Ush[2 * 16 + ((k0 << 1) | t8) * 4].x);
    f2i[k0] = rfl(Ush[2 * 16 + ((k0 << 1) | t8) * 4].y);
  }
  const float f3r = rfl(Ush[3 * 16 + t76 * 4].x), f3i = rfl(Ush[3 * 16 + t76 * 4].y);
  const float2 f4 = Ush[4 * 16 + t54 * 4];
  const float2 f5 = Ush[5 * 16 + t32 * 4];
  const float2 f6 = Ush[6 * 16 + t10 * 4];
  float cr = f3r * f4.x - f3i * f4.y, ci = f3r * f4.y + f3i * f4.x, tr, ti;
  tr = cr * f5.x - ci * f5.y; ti = cr * f5.y + ci * f5.x; cr = tr; ci = ti;
  tr = cr * f6.x - ci * f6.y; ti = cr * f6.y + ci * f6.x; cr = tr; ci = ti;
  float g2r[2], g2i[2];
  #pragma unroll
  for (int k0 = 0; k0 < 2; ++k0) {
    g2r[k0] = f2r[k0] * cr - f2i[k0] * ci;
    g2i[k0] = f2r[k0] * ci + f2i[k0] * cr;
  }
  float vr[16], vi[16];
  #pragma unroll
  for (int k = 0; k < 16; ++k) {
    const int k3 = k >> 3, k21 = (k >> 1) & 3, k0 = k & 1;
    const float hr2 = f0r[k3] * f1r[k21] - f0i[k3] * f1i[k21];
    const float hi2 = f0r[k3] * f1i[k21] + f0i[k3] * f1r[k21];
    vr[k] = hr2 * g2r[k0] - hi2 * g2i[k0];
    vi[k] = hr2 * g2i[k0] + hi2 * g2r[k0];
  }
  gate_pair16(Ush + 7 * 16, Ush + 8 * 16, vr, vi);   // q1 (bits 12,11), q3 (10,9)
  constexpr int m = (1 << 9) - 1;
  const int a0 = ef_c(((tid & ~m) << 4) | (tid & m));
  #pragma unroll
  for (int k = 0; k < 16; ++k)
    st[a0 ^ ef_c(k << 9)] = make_float2(vr[k], vi[k]);
  __syncthreads();
}

// ---- WAVE-LOCAL SU4 pair pass (SH+4 <= 10): NO barrier ----
template<int SH>
__device__ __forceinline__ void su4_pairW(float2* __restrict__ st,
                                          const float2* __restrict__ ugA,
                                          const float2* __restrict__ ugB,
                                          int tid) {
  const int w = tid >> 6, l = tid & 63;
  constexpr int m = (1 << SH) - 1;
  const int a0 = ef_c((w << 10) | ((l & ~m) << 4) | (l & m));
  float vr[16], vi[16];
  #pragma unroll
  for (int k = 0; k < 16; ++k) {
    const float2 v = st[a0 ^ ef_c(k << SH)];
    vr[k] = v.x; vi[k] = v.y;
  }
  gate_pair16(ugA, ugB, vr, vi);
  #pragma unroll
  for (int k = 0; k < 16; ++k)
    st[a0 ^ ef_c(k << SH)] = make_float2(vr[k], vi[k]);
}

template<int J>
__device__ __forceinline__ void bfly16(float c, float s, float pr[16], float pi_[16]) {
  #pragma unroll
  for (int i = 0; i < 16; ++i) {
    if ((i & (1 << J)) == 0) {
      const int j = i | (1 << J);
      const float ar = pr[i], ai = pi_[i], br = pr[j], bi = pi_[j];
      pr[i]  = fmaf(c, ar, -(s * br));
      pi_[i] = fmaf(c, ai, -(s * bi));
      pr[j]  = fmaf(s, ar, c * br);
      pi_[j] = fmaf(s, ai, c * bi);
    }
  }
}

// ---- WAVE-LOCAL 4-qubit RY pass at SH=6 (qubits 4..7): NO barrier ----
__device__ __forceinline__ void ry4W6(float2* __restrict__ st,
                                      const float* __restrict__ rc,
                                      const float* __restrict__ rs, int tid) {
  const float c3 = rfl(rc[4]), s3 = rfl(rs[4]);
  const float c2 = rfl(rc[5]), s2 = rfl(rs[5]);
  const float c1 = rfl(rc[6]), s1 = rfl(rs[6]);
  const float c0 = rfl(rc[7]), s0 = rfl(rs[7]);
  const int w = tid >> 6, l = tid & 63;
  const int a0 = ef_c((w << 10) | l);   // SH=6: (l&~63)<<4 == 0
  float vr[16], vi[16];
  #pragma unroll
  for (int k = 0; k < 16; ++k) {
    const float2 v = st[a0 ^ ef_c(k << 6)];
    vr[k] = v.x; vi[k] = v.y;
  }
  bfly16<3>(c3, s3, vr, vi);
  bfly16<2>(c2, s2, vr, vi);
  bfly16<1>(c1, s1, vr, vi);
  bfly16<0>(c0, s0, vr, vi);
  #pragma unroll
  for (int k = 0; k < 16; ++k)
    st[a0 ^ ef_c(k << 6)] = make_float2(vr[k], vi[k]);
}

// ---- WAVE-LOCAL RY pass at SH=2 (qubits 8..11) + DPP butterflies for
// qubits 12,13 (y-bits 1,0 = lane bits 1,0, quad-aligned). R13-proven.
__device__ __forceinline__ void ry4W2d(float2* __restrict__ st,
                                       const float* __restrict__ rc,
                                       const float* __restrict__ rs, int tid) {
  const float c3 = rfl(rc[8]),  s3 = rfl(rs[8]);
  const float c2 = rfl(rc[9]),  s2 = rfl(rs[9]);
  const float c1 = rfl(rc[10]), s1 = rfl(rs[10]);
  const float c0 = rfl(rc[11]), s0 = rfl(rs[11]);
  const float cA = rfl(rc[12]), sA = rfl(rs[12]);   // qubit 12 -> y bit 1
  const float cB = rfl(rc[13]), sB = rfl(rs[13]);   // qubit 13 -> y bit 0
  const int w = tid >> 6, l = tid & 63;
  const int a0 = ef_c((w << 10) | ((l & ~3) << 4) | (l & 3));
  float vr[16], vi[16];
  #pragma unroll
  for (int k = 0; k < 16; ++k) {
    const float2 v = st[a0 ^ ef_c(k << 2)];
    vr[k] = v.x; vi[k] = v.y;
  }
  bfly16<3>(c3, s3, vr, vi);
  bfly16<2>(c2, s2, vr, vi);
  bfly16<1>(c1, s1, vr, vi);
  bfly16<0>(c0, s0, vr, vi);
  {
    const float se = (l & 1) ? sB : -sB;
    #pragma unroll
    for (int k = 0; k < 16; ++k) {
      const float pr = fdpp<0xB1>(vr[k]), pi_ = fdpp<0xB1>(vi[k]);
      vr[k] = fmaf(cB, vr[k], se * pr);
      vi[k] = fmaf(cB, vi[k], se * pi_);
    }
  }
  {
    const float se = (l & 2) ? sA : -sA;
    #pragma unroll
    for (int k = 0; k < 16; ++k) {
      const float pr = fdpp<0x4E>(vr[k]), pi_ = fdpp<0x4E>(vi[k]);
      vr[k] = fmaf(cA, vr[k], se * pr);
      vi[k] = fmaf(cA, vi[k], se * pi_);
    }
  }
  #pragma unroll
  for (int k = 0; k < 16; ++k)
    st[a0 ^ ef_c(k << 2)] = make_float2(vr[k], vi[k]);
}

// ---- block reduce: 4 DPP (VALU) + 2 shfl_xor stages; xor masks {1,2,7,15,16,32}
// span all 64 lanes (group-generated). Saves 4 LDS-pipe ops per reduce.
__device__ __forceinline__ void reduce_store(float a, float* slot, int lane, int wid) {
  a += fdpp<0xB1>(a);    // xor 1
  a += fdpp<0x4E>(a);    // xor 2
  a += fdpp<0x141>(a);   // half-mirror = xor 7
  a += fdpp<0x140>(a);   // mirror = xor 15
  a += __shfl_xor(a, 16, 64);
  a += __shfl_xor(a, 32, 64);
  if (lane == 0) slot[wid] = a;
}

// ---- fused RY(q0..3) + CNOT-chain pass.
// FINAL: obs0, obs1 ONLY (both have y10 fixed inside pairs -> register-local;
// obs2 flips y10 -> must go through LDS: R14's bug). YM index map, no copy.
template<bool FINAL>
__device__ __forceinline__ void perm_ry_pass(float2* __restrict__ st,
                                             const float* __restrict__ rc,
                                             const float* __restrict__ rs,
                                             int tid,
                                             const float2* __restrict__ Hsh,
                                             float (*red)[TCIRC / 64],
                                             int lane, int wid) {
  const float c0 = rfl(rc[0]), s0 = rfl(rs[0]);
  const float c1 = rfl(rc[1]), s1 = rfl(rs[1]);
  const float c2 = rfl(rc[2]), s2 = rfl(rs[2]);
  const float c3 = rfl(rc[3]), s3 = rfl(rs[3]);
  __syncthreads();   // wave-local writers from prior passes must land
  const int Er = ef_c(tid);
  float pr[16], pi_[16];
  #pragma unroll
  for (int i = 0; i < 16; ++i) {
    const float2 v = st[Er ^ ef_c(i << 10)];
    pr[i] = v.x; pi_[i] = v.y;
  }
  __syncthreads();
  bfly16<3>(c0, s0, pr, pi_);
  bfly16<2>(c1, s1, pr, pi_);
  bfly16<1>(c2, s2, pr, pi_);
  bfly16<0>(c3, s3, pr, pi_);
  const int Ew = ef_c(siginv_c(tid));
  #pragma unroll
  for (int i = 0; i < 16; ++i)
    st[Ew ^ ef_c(siginv_c(i << 10))] = make_float2(pr[i], pi_[i]);
  if (FINAL) {
    reduce_store(qform16<0, true>(Hsh + 0 * 16, pr, pi_), red[0], lane, wid); // y13,y12
    reduce_store(qform16<1, true>(Hsh + 1 * 16, pr, pi_), red[1], lane, wid); // y12,y11
  }
  __syncthreads();
}

// ---- obs window pass: 4-bit window bits SH+3..SH (R12-proven tiling) ----
// NOB==3: MODE0/1/2 at obase..obase+2. NOB==2: MODE1, MODE2 (SH=0: obs11,12).
template<int SH, int NOB>
__device__ __forceinline__ void obs_tri(const float2* __restrict__ st,
                                        const float2* __restrict__ Hsh, int obase,
                                        float (*red)[TCIRC / 64],
                                        int lane, int wid, int tid) {
  constexpr int m = (1 << SH) - 1;
  const int a0 = ef_c(((tid & ~m) << 4) | (tid & m));
  float vr[16], vi[16];
  #pragma unroll
  for (int k = 0; k < 16; ++k) {
    const float2 v = st[a0 ^ ef_c(k << SH)];
    vr[k] = v.x; vi[k] = v.y;
  }
  if (NOB == 3) {
    reduce_store(qform16<0, false>(Hsh + (obase + 0) * 16, vr, vi), red[obase + 0], lane, wid);
    reduce_store(qform16<1, false>(Hsh + (obase + 1) * 16, vr, vi), red[obase + 1], lane, wid);
    reduce_store(qform16<2, false>(Hsh + (obase + 2) * 16, vr, vi), red[obase + 2], lane, wid);
  } else {
    reduce_store(qform16<1, false>(Hsh + (obase + 0) * 16, vr, vi), red[obase + 0], lane, wid);
    reduce_store(qform16<2, false>(Hsh + (obase + 1) * 16, vr, vi), red[obase + 1], lane, wid);
  }
}

// ====== single fused kernel: encoder + U-build (shfl-parallel) + circuit ====
__launch_bounds__(TCIRC, 1)
__global__ void circuit_kernel(const float* __restrict__ x,
                               const float* __restrict__ W1,
                               const float* __restrict__ b1,
                               const float* __restrict__ W2,
                               const float* __restrict__ b2,
                               const float* __restrict__ vp,
                               const float* __restrict__ oA,
                               const float* __restrict__ oB,
                               const float* __restrict__ oD,
                               float* __restrict__ out) {
  __shared__ float2 st[DIM];                 // 128 KiB (head: scratch overlay)
  __shared__ float2 Ush[NGATES * 16];
  __shared__ float2 Hsh[NOBSN * 16];
  __shared__ float  ryc[DEPTHN * NQ];
  __shared__ float  rys[DEPTHN * NQ];
  __shared__ float  red[NOBSN][TCIRC / 64];

  const int b = blockIdx.x;
  const int tid = threadIdx.x;

  // ---- head scratch overlaid on the not-yet-initialized state ----
  float* base = (float*)st;
  float* xrow = base;          // 256
  float* hrow = base + 256;    // 256
  float* encs = base + 512;    // 195
  float* part = base + 1024;   // 1024

  // trig + observable H on disjoint high threads (independent of encoder)
  if (tid >= 960 && tid < 960 + DEPTHN * NQ) {
    const int i = tid - 960;
    const float h = 0.5f * vp[i];
    ryc[i] = cosf(h); rys[i] = sinf(h);
  }
  if (tid >= 832 && tid < 832 + NOBSN) {
    const int o = tid - 832;
    const int rr[6] = {1, 2, 2, 3, 3, 3};
    const int cc[6] = {0, 0, 1, 0, 1, 2};
    float2 H[16];
    #pragma unroll
    for (int i = 0; i < 16; ++i) H[i] = make_float2(0.f, 0.f);
    for (int m = 0; m < 6; ++m) {
      const float a = oA[o * 6 + m], bb = oB[o * 6 + m];
      H[rr[m] * 4 + cc[m]] = make_float2(a, bb);
      H[cc[m] * 4 + rr[m]] = make_float2(a, -bb);
    }
    H[0]  = make_float2(2.f * oD[o * 4 + 1], 0.f);
    H[5]  = make_float2(2.f * oD[o * 4 + 2], 0.f);
    H[10] = make_float2(2.f * oD[o * 4 + 3], 0.f);
    for (int i = 0; i < 16; ++i) Hsh[o * 16 + i] = H[i];
  }
  if (tid < INDIM) xrow[tid] = x[b * INDIM + tid];
  __syncthreads();

  {  // hrow partials: 4 threads per output, float4 loads
    const int o = tid & 255, q = tid >> 8;
    const float4* wp = (const float4*)(W1 + o * INDIM + q * 64);
    const float4* xq = (const float4*)(xrow + q * 64);
    float a = 0.f;
    #pragma unroll 4
    for (int k = 0; k < 16; ++k) {
      const float4 wv = wp[k], xv = xq[k];
      a = fmaf(wv.x, xv.x, fmaf(wv.y, xv.y, fmaf(wv.z, xv.z, fmaf(wv.w, xv.w, a))));
    }
    part[(q << 8) | o] = a;
  }
  __syncthreads();
  if (tid < HIDDIM) {
    const float a = b1[tid] + part[tid] + part[256 + tid] + part[512 + tid] + part[768 + tid];
    hrow[tid] = a / (1.f + expf(-a));
  }
  __syncthreads();
  {  // enc partials
    const int o = tid & 255, q = tid >> 8;
    if (o < ENCDIM) {
      const float4* wp = (const float4*)(W2 + o * HIDDIM + q * 64);
      const float4* hq = (const float4*)(hrow + q * 64);
      float a = 0.f;
      #pragma unroll 4
      for (int k = 0; k < 16; ++k) {
        const float4 wv = wp[k], hv = hq[k];
        a = fmaf(wv.x, hv.x, fmaf(wv.y, hv.y, fmaf(wv.z, hv.z, fmaf(wv.w, hv.w, a))));
      }
      part[(q << 8) | o] = a;
    }
  }
  __syncthreads();
  if (tid < ENCDIM)
    encs[tid] = b2[tid] + part[tid] + part[256 + tid] + part[512 + tid] + part[768 + tid];
  __syncthreads();

  // ---- U-build: 16 lanes per gate, matmuls via shfl (no barriers inside) ----
  if (tid < NGATES * 16) {
    const int g = tid >> 4, e = tid & 15, i = e >> 2, j = e & 3;
    const float* th = encs + g * NGEN;
    float Are = 0.f, Aie = 0.f;
    for (int t = 0; t < NGEN; ++t) {
      const int p = t + 1;
      const int pa = p >> 2, pb = p & 3;
      const float ar = c_PR[pa][i >> 1][j >> 1], ai = c_PI[pa][i >> 1][j >> 1];
      const float br = c_PR[pb][i & 1][j & 1],  bi = c_PI[pb][i & 1][j & 1];
      Are = fmaf(th[t], ar * br - ai * bi, Are);
      Aie = fmaf(th[t], ar * bi + ai * br, Aie);
    }
    float r = sqrtf(Are * Are + Aie * Aie);
    r += __shfl_xor(r, 1, 16);
    r += __shfl_xor(r, 2, 16);
    float nrm = r;
    nrm = fmaxf(nrm, __shfl_xor(nrm, 4, 16));
    nrm = fmaxf(nrm, __shfl_xor(nrm, 8, 16));
    int sct = 0;
    float scale = 1.f;
    while (nrm * scale > 0.5f && sct < 30) { scale *= 0.5f; ++sct; }
    const float Mre = -Aie * scale, Mie = Are * scale;   // M = i*A*scale
    float Rr = (i == j) ? 1.f : 0.f, Ri = 0.f;
    for (int k = 10; k >= 1; --k) {
      const float inv = 1.f / (float)k;
      float tr = 0.f, ti = 0.f;
      #pragma unroll
      for (int l = 0; l < 4; ++l) {
        const float mr = __shfl(Mre, i * 4 + l, 16), mi = __shfl(Mie, i * 4 + l, 16);
        const float rr2 = __shfl(Rr, l * 4 + j, 16), ri2 = __shfl(Ri, l * 4 + j, 16);
        tr = fmaf(mr, rr2, fmaf(-mi, ri2, tr));
        ti = fmaf(mr, ri2, fmaf(mi, rr2, ti));
      }
      Rr = ((i == j) ? 1.f : 0.f) + inv * tr;
      Ri = inv * ti;
    }
    for (int it = 0; it < sct; ++it) {
      float tr = 0.f, ti = 0.f;
      #pragma unroll
      for (int l = 0; l < 4; ++l) {
        const float ar = __shfl(Rr, i * 4 + l, 16), ai2 = __shfl(Ri, i * 4 + l, 16);
        const float br = __shfl(Rr, l * 4 + j, 16), bi2 = __shfl(Ri, l * 4 + j, 16);
        tr = fmaf(ar, br, fmaf(-ai2, bi2, tr));
        ti = fmaf(ar, bi2, fmaf(ai2, br, ti));
      }
      Rr = tr; Ri = ti;
    }
    Ush[g * 16 + e] = make_float2(Rr, Ri);
  }
  __syncthreads();

  // ---- fused: even-layer product state + odd gates q1,q3 (one pass, 0 reads)
  init_pair9(st, Ush, tid);

  // ---- remaining odd layer: 2 wave-local passes ----
  su4_pairW<5>(st, Ush + 9 * 16, Ush + 10 * 16, tid);  // q5,q7 (bits 8..5)
  su4_pairW<1>(st, Ush + 11 * 16, Ush + 12 * 16, tid); // q9,q11 (bits 4..1)

  // ---- variational depths: 2 wave-local RY passes + fused perm+RY(0..3) ----
  const int lane = tid & 63, wid = tid >> 6;
  #pragma unroll 1
  for (int d = 0; d < DEPTHN - 1; ++d) {
    const float* rc = ryc + d * NQ;
    const float* rs = rys + d * NQ;
    ry4W6(st, rc, rs, tid);                                // qubits 4..7
    ry4W2d(st, rc, rs, tid);                               // qubits 8..13 (DPP)
    perm_ry_pass<false>(st, rc, rs, tid, Hsh, red, lane, wid);
  }
  {  // final depth: perm pass also computes obs0, obs1 in-register
    const float* rc = ryc + (DEPTHN - 1) * NQ;
    const float* rs = rys + (DEPTHN - 1) * NQ;
    ry4W6(st, rc, rs, tid);
    ry4W2d(st, rc, rs, tid);
    perm_ry_pass<true>(st, rc, rs, tid, Hsh, red, lane, wid);
  }

  // ---- remaining observables: 4 read-only window passes (R12-proven tiling)
  obs_tri<8, 3>(st, Hsh, 2, red, lane, wid, tid);   // obs2 (11,10), obs3, obs4
  obs_tri<5, 3>(st, Hsh, 5, red, lane, wid, tid);   // obs5 (8,7),  obs6, obs7
  obs_tri<2, 3>(st, Hsh, 8, red, lane, wid, tid);   // obs8 (5,4),  obs9, obs10
  obs_tri<0, 2>(st, Hsh, 11, red, lane, wid, tid);  // obs11 (2,1), obs12 (1,0)

  __syncthreads();
  if (tid < NOBSN) {
    float s = 0.f;
    #pragma unroll
    for (int w = 0; w < TCIRC / 64; ++w) s += red[tid][w];
    out[b * NOBSN + tid] = s;
  }
}

extern "C" void kernel_launch(void* const* d_in, const int* in_sizes, int n_in,
                              void* d_out, int out_size, void* d_ws, size_t ws_size,
                              hipStream_t stream) {
  const float* x  = (const float*)d_in[0];
  const float* W1 = (const float*)d_in[1];
  const float* b1 = (const float*)d_in[2];
  const float* W2 = (const float*)d_in[3];
  const float* b2 = (const float*)d_in[4];
  const float* vp = (const float*)d_in[5];
  const float* oA = (const float*)d_in[6];
  const float* oB = (const float*)d_in[7];
  const float* oD = (const float*)d_in[8];
  float* out = (float*)d_out;

  circuit_kernel<<<BATCHN, TCIRC, 0, stream>>>(x, W1, b1, W2, b2, vp, oA, oB, oD, out);
}